// Round 4
// baseline (43.330 us; speedup 1.0000x reference)
//
#include <hip/hip_runtime.h>

#define NFEAT 40
#define EMB   64
#define ATT   32
#define NPAIR 780
#define NT    25      // 25 tiles x 32 pairs = 800 (padded)
#define XH_S  72      // fp16 x LDS stride (elems) -> 144 B row stride

typedef __attribute__((ext_vector_type(8)))  _Float16 f16x8;
typedef __attribute__((ext_vector_type(4)))  _Float16 f16x4;
typedef __attribute__((ext_vector_type(16))) float    f32x16;

template <int CTRL>
__device__ __forceinline__ float dpp_add_f(float v) {
  int t = __builtin_amdgcn_update_dpp(0, __float_as_int(v), CTRL, 0xF, 0xF, true);
  return v + __int_as_float(t);
}
__device__ __forceinline__ float rowsum16(float v) {
  v = dpp_add_f<0x128>(v);
  v = dpp_add_f<0x124>(v);
  v = dpp_add_f<0x122>(v);
  v = dpp_add_f<0x121>(v);
  return v;
}

__device__ __forceinline__ int pair_off(int i) { return 39 * i - (i * (i - 1)) / 2; }

extern "C" __global__ __launch_bounds__(256)
void afm_kernel(const float* __restrict__ xg, const float* __restrict__ Wg,
                const float* __restrict__ bg, const float* __restrict__ hg,
                const float* __restrict__ pg, float* __restrict__ outg, int nbatch) {
  __shared__ __align__(16) _Float16 xh[NFEAT * XH_S];   // 5760 B
  __shared__ float red[4][2];

  const int tid  = threadIdx.x;
  const int lane = tid & 63, wid = tid >> 6;
  const int l31  = lane & 31, hi = lane >> 5;

  // ---- once per block: W / p fragments (A-operands of 32x32x16) ----
  // A layout: row m = lane&31, k = (lane>>5)*8 + t  (8 contiguous k per lane)
  f16x8 wfA[4], pA[4];
#pragma unroll
  for (int kk = 0; kk < 4; kk++) {
    f16x8 rw, rp;
#pragma unroll
    for (int t = 0; t < 8; t++) {
      int krow = kk * 16 + hi * 8 + t;
      rw[t] = (_Float16)Wg[krow * ATT + l31];
      _Float16 pv = (_Float16)pg[krow];
      rp[t] = (l31 == 0) ? pv : (_Float16)0.f;   // rows 1..31 of A are zero
    }
    wfA[kk] = rw; pA[kk] = rp;
  }
  // per-lane bias/h by acc reg: att(reg) = (reg&3) + 8*(reg>>2) + 4*hi
  float br[16], hr[16];
#pragma unroll
  for (int r = 0; r < 16; r++) {
    int att = (r & 3) + 8 * (r >> 2) + 4 * hi;
    br[r] = bg[att];
    hr[r] = hg[att];
  }

  // ---- once per block: per-wave pair offsets (registers, no LDS table) ----
  unsigned pij[7];
#pragma unroll
  for (int t = 0; t < 7; t++) {
    int p = (wid + 4 * t) * 32 + l31;
    int i = 0, j = 0;
    if (p < NPAIR) {
      i = (int)((79.0f - sqrtf(6241.0f - 8.0f * (float)p)) * 0.5f);
      if (i < 0) i = 0;
      while (pair_off(i + 1) <= p) ++i;
      while (pair_off(i) > p) --i;
      j = i + 1 + (p - pair_off(i));
    }
    pij[t] = (unsigned)(i * 144 + hi * 16) | ((unsigned)(j * 144 + hi * 16) << 16);
  }

  // ---- 2 batches per block ----
  for (int it = 0; it < 2; it++) {
    const int bb = blockIdx.x * 2 + it;
    if (bb >= nbatch) break;

    const float4* xsrc = (const float4*)(xg + (size_t)bb * (NFEAT * EMB));
    for (int f = tid; f < NFEAT * EMB / 4; f += 256) {
      float4 v = xsrc[f];
      int row = f >> 4, c = (f & 15) * 4;
      f16x4 h4 = {(_Float16)v.x, (_Float16)v.y, (_Float16)v.z, (_Float16)v.w};
      *(f16x4*)&xh[row * XH_S + c] = h4;
    }
    __syncthreads();

    float sum_e = 0.f, sum_es = 0.f;
#pragma unroll
    for (int t = 0; t < 7; t++) {
      if (t < 6 || wid == 0) {            // tiles m = wid + 4t < 25
        const unsigned offi = pij[t] & 0xFFFFu;
        const unsigned offj = pij[t] >> 16;
        f32x16 acc  = {0.f};
        f32x16 acc2 = {0.f};
#pragma unroll
        for (int kk = 0; kk < 4; kk++) {
          const f16x8 xi = *(const f16x8*)((const char*)xh + offi + kk * 32);
          const f16x8 xj = *(const f16x8*)((const char*)xh + offj + kk * 32);
          f16x8 af = xi * xj;             // 4x v_pk_mul_f16
          acc  = __builtin_amdgcn_mfma_f32_32x32x16_f16(wfA[kk], af, acc,  0, 0, 0);
          acc2 = __builtin_amdgcn_mfma_f32_32x32x16_f16(pA[kk],  af, acc2, 0, 0, 0);
        }
        // logit: 16 atts in-lane, partner 16 via ^32
        float v = 0.f;
#pragma unroll
        for (int r = 0; r < 16; r++)
          v = fmaf(fmaxf(acc[r] + br[r], 0.f), hr[r], v);
        v += __shfl_xor(v, 32, 64);
        float s = acc2[0];                // D2 row0 (hi==0) else exact 0
        s += __shfl_xor(s, 32, 64);       // both halves now hold s_p
        int p = (wid + 4 * t) * 32 + l31;
        float e = (p < NPAIR) ? __expf(v) : 0.f;
        sum_e += e;                       // each pair counted 2x (both halves)
        sum_es = fmaf(e, s, sum_es);      // also 2x -> cancels in ratio
      }
    }

    // wave reduce then block reduce
    sum_e = rowsum16(sum_e);
    sum_e += __shfl_xor(sum_e, 16, 64);
    sum_e += __shfl_xor(sum_e, 32, 64);
    sum_es = rowsum16(sum_es);
    sum_es += __shfl_xor(sum_es, 16, 64);
    sum_es += __shfl_xor(sum_es, 32, 64);
    if (lane == 0) { red[wid][0] = sum_e; red[wid][1] = sum_es; }
    __syncthreads();
    if (tid == 0) {
      float Z = red[0][0] + red[1][0] + red[2][0] + red[3][0];
      float S = red[0][1] + red[1][1] + red[2][1] + red[3][1];
      outg[bb] = S / Z;
    }
  }
}

extern "C" void kernel_launch(void* const* d_in, const int* in_sizes, int n_in,
                              void* d_out, int out_size, void* d_ws, size_t ws_size,
                              hipStream_t stream) {
  const float* xg = (const float*)d_in[0];
  const float* Wg = (const float*)d_in[1];
  const float* bg = (const float*)d_in[2];
  const float* hg = (const float*)d_in[3];
  const float* pg = (const float*)d_in[4];
  float* outg = (float*)d_out;
  const int Bn = in_sizes[0] / (NFEAT * EMB);
  const int nblk = (Bn + 1) / 2;
  afm_kernel<<<dim3(nblk), dim3(256), 0, stream>>>(xg, Wg, bg, hg, pg, outg, Bn);
}